// Round 3
// baseline (1197.261 us; speedup 1.0000x reference)
//
#include <hip/hip_runtime.h>
#include <cstdint>
#include <cstddef>

#define N_NODES 100000
#define D_IN 512
#define ALPHA 0.1f
#define EPS_BN 1e-5f
#define M_TILE 128
#define BK 64
#define NBUCKET 3125          // 100000 / 32 exactly
#define BSHIFT 5              // 32 nodes per bucket
#define BUCKETS_PER_XCD 391   // ceil(3125/8)

typedef float f32x4 __attribute__((ext_vector_type(4)));
typedef __bf16 bf16x8 __attribute__((ext_vector_type(8)));
typedef unsigned short u16x8 __attribute__((ext_vector_type(8)));
typedef unsigned short u16x4 __attribute__((ext_vector_type(4)));

__device__ __forceinline__ unsigned short f2bf(float f) {
  unsigned u = __float_as_uint(f);
  u += 0x7fffu + ((u >> 16) & 1u);   // RNE
  return (unsigned short)(u >> 16);
}
__device__ __forceinline__ float bf2f(unsigned short h) {
  return __uint_as_float(((unsigned)h) << 16);
}

// ---------------- prep: fold BN into weights (bf16) + biases, zero deg + bucket cursors ----------------
__global__ void k_prep(const float* __restrict__ w1, const float* __restrict__ b1,
                       const float* __restrict__ g1, const float* __restrict__ be1,
                       const float* __restrict__ m1, const float* __restrict__ v1,
                       const float* __restrict__ w2, const float* __restrict__ b2,
                       const float* __restrict__ g2, const float* __restrict__ be2,
                       const float* __restrict__ m2, const float* __restrict__ v2,
                       unsigned short* __restrict__ w1b, unsigned short* __restrict__ w2b,
                       float* __restrict__ bias1, float* __restrict__ bias2,
                       int* __restrict__ deg, int* __restrict__ bcur,
                       int* __restrict__ xcd_next) {
  int idx = blockIdx.x * 256 + threadIdx.x;
  if (idx < 65536) {                       // w1: [128][512], scale row n by s1[n]
    int n = idx >> 9;
    float s = g1[n] * rsqrtf(v1[n] + EPS_BN);
    w1b[idx] = f2bf(w1[idx] * s);
  } else if (idx < 81920) {                // w2: [128][128]
    int i = idx - 65536;
    int n = i >> 7;
    float s = g2[n] * rsqrtf(v2[n] + EPS_BN);
    w2b[i] = f2bf(w2[i] * s);
  } else if (idx < 82048) {
    int c = idx - 81920;
    float s = g1[c] * rsqrtf(v1[c] + EPS_BN);
    bias1[c] = (b1[c] - m1[c]) * s + be1[c];
  } else if (idx < 82176) {
    int c = idx - 82048;
    float s = g2[c] * rsqrtf(v2[c] + EPS_BN);
    bias2[c] = (b2[c] - m2[c]) * s + be2[c];
  }
  int di = idx - 82176;
  if (di >= 0 && di < N_NODES) deg[di] = 0;
  int bi = di - N_NODES;
  if (bi >= 0 && bi < NBUCKET) bcur[bi] = 0;
  if (bi >= NBUCKET && bi < NBUCKET + 8) xcd_next[bi - NBUCKET] = 0;
}

// ---------------- in-degree histogram ----------------
__global__ void k_degree(const int* __restrict__ dst, int E, int* __restrict__ deg) {
  int e = blockIdx.x * 256 + threadIdx.x;
  if (e < E) atomicAdd(&deg[dst[e]], 1);
}

// ---------------- 3-level exclusive scan of deg -> row_start ----------------
__global__ void k_scan1(const int* __restrict__ deg, int* __restrict__ bsum) {
  __shared__ int red[256];
  int t = threadIdx.x;
  int i = blockIdx.x * 256 + t;
  red[t] = (i < N_NODES) ? deg[i] : 0;
  __syncthreads();
  for (int off = 128; off > 0; off >>= 1) {
    if (t < off) red[t] += red[t + off];
    __syncthreads();
  }
  if (t == 0) bsum[blockIdx.x] = red[0];
}

#define NB_SCAN 391
__global__ void k_scan2(int* __restrict__ bsum) {
  __shared__ int s[448];
  int t = threadIdx.x;
  for (int i = t; i < 448; i += 256) s[i] = (i < NB_SCAN) ? bsum[i] : 0;
  __syncthreads();
  if (t < 64) {
    int base = t * 7;
    int vals[7];
    int sum = 0;
#pragma unroll
    for (int j = 0; j < 7; ++j) { vals[j] = s[base + j]; sum += vals[j]; }
    int x = sum;
#pragma unroll
    for (int off = 1; off < 64; off <<= 1) {
      int y = __shfl_up(x, off, 64);
      if (t >= off) x += y;
    }
    int run = x - sum;   // exclusive prefix of lane sums
#pragma unroll
    for (int j = 0; j < 7; ++j) { int tmp = vals[j]; s[base + j] = run; run += tmp; }
  }
  __syncthreads();
  for (int i = t; i < NB_SCAN; i += 256) bsum[i] = s[i];
}

__global__ void k_scan3(const int* __restrict__ deg, const int* __restrict__ bsum,
                        int* __restrict__ row_start, float* __restrict__ dinv, int E) {
  __shared__ int sb[2][256];
  int t = threadIdx.x;
  int i = blockIdx.x * 256 + t;
  int d = (i < N_NODES) ? deg[i] : 0;
  sb[0][t] = d;
  __syncthreads();
  int cur = 0;
#pragma unroll
  for (int off = 1; off < 256; off <<= 1) {
    int val = sb[cur][t] + ((t >= off) ? sb[cur][t - off] : 0);
    sb[cur ^ 1][t] = val;
    __syncthreads();
    cur ^= 1;
  }
  int incl = sb[cur][t];
  int ex = incl - d;
  if (i < N_NODES) {
    int rs = bsum[blockIdx.x] + ex;
    row_start[i] = rs;
    dinv[i] = rsqrtf((float)(d + 1));   // +1 self-loop
  }
  if (i == N_NODES) row_start[N_NODES] = E;
}

// ---------------- bucket scatter phase A (XCD-partitioned): only the owning XCD writes a bucket ----------------
// Each csr_col cache line is then produced by exactly one XCD's L2 -> ~1 writeback per line
// instead of ~8 (cross-XCD partial-line bounce seen in rounds 1-2: WRITE_SIZE 161-195 MB for 12.8 MB payload).
__global__ void k_bucketA(const int* __restrict__ src, const int* __restrict__ dst, int E,
                          const int* __restrict__ row_start, int* __restrict__ bcur,
                          unsigned* __restrict__ csr_col, int* __restrict__ xcd_next) {
  __shared__ int sc;
  // HW_REG_XCC_ID: id=20, offset=0, size=32 -> simm16 = 20 | (31<<11) = 63508 [measured: learn_hip m09]
  int x = __builtin_amdgcn_s_getreg(63508) & 7;
  const int CHUNK = 2048;
  int nchunk = (E + CHUNK - 1) / CHUNK;
  for (;;) {
    __syncthreads();
    if (threadIdx.x == 0) sc = atomicAdd(&xcd_next[x], 1);
    __syncthreads();
    int c = sc;
    if (c >= nchunk) break;
    int e0 = c * CHUNK;
    int n = E - e0; if (n > CHUNK) n = CHUNK;
    for (int i = threadIdx.x; i < n; i += 256) {
      int e = e0 + i;
      int d = dst[e];
      int b = d >> BSHIFT;
      int p = b / BUCKETS_PER_XCD; if (p > 7) p = 7;
      if (p == x) {
        int s = src[e];
        int base = row_start[b << BSHIFT];
        int pos = atomicAdd(&bcur[b], 1);
        csr_col[base + pos] = (unsigned)s | ((unsigned)(d & 31) << 17);
      }
    }
  }
}

// ---------------- bucket scatter phase B: in-place sort within bucket via LDS cursors ----------------
__global__ __launch_bounds__(256) void k_bucketB(const int* __restrict__ row_start,
                                                 unsigned* __restrict__ csr_col) {
  __shared__ int lcur[32];
  __shared__ unsigned lout[3072];
  int b = blockIdx.x;
  int node0 = b << BSHIFT;
  int t = threadIdx.x;
  int base = row_start[node0];
  int end = row_start[node0 + 32];
  if (t < 32) lcur[t] = row_start[node0 + t] - base;
  __syncthreads();
  int cnt = end - base;
  for (int i = t; i < cnt; i += 256) {
    unsigned v = csr_col[base + i];
    unsigned s = v & 0x1FFFFu;
    int ld = (int)(v >> 17);
    int p = atomicAdd(&lcur[ld], 1);
    if (p < 3072) lout[p] = s;
  }
  __syncthreads();
  for (int i = t; i < cnt; i += 256) csr_col[base + i] = lout[i];
}

// ---------------- fused MLP: x -> h0[N,4], zt0 = dinv*h0 ----------------
__global__ __launch_bounds__(256, 2) void k_mlp(
    const float* __restrict__ x, const unsigned short* __restrict__ w1b,
    const unsigned short* __restrict__ w2b, const float* __restrict__ bias1,
    const float* __restrict__ bias2, const float* __restrict__ w3,
    const float* __restrict__ b3, const float* __restrict__ dinv,
    float4* __restrict__ h0, float4* __restrict__ zt) {
  __shared__ unsigned short arena[35840];
  __shared__ float lds_w3[384];
  unsigned short* lds_x = arena;
  unsigned short* lds_w = arena + 9216;
  unsigned short* lds_h = arena;
  unsigned short* lds_w2 = arena + 18432;

  const int tid = threadIdx.x;
  const int lane = tid & 63;
  const int wv = tid >> 6;
  const int fr = lane & 15;
  const int kq = (lane >> 4) * 8;
  const int rq = (lane >> 4) * 4;
  const int row0 = blockIdx.x * M_TILE;

  for (int i = tid; i < 384; i += 256) lds_w3[i] = w3[i];

#pragma unroll
  for (int it = 0; it < 8; ++it) {
    int idx = it * 256 + tid;
    int n = idx >> 4, c8 = idx & 15;
    uint4 v = *(const uint4*)(w2b + n * 128 + c8 * 8);
    *(uint4*)(lds_w2 + n * 136 + c8 * 8) = v;
  }

  f32x4 zero4 = {0.f, 0.f, 0.f, 0.f};
  f32x4 acc[2][8];
#pragma unroll
  for (int mt = 0; mt < 2; ++mt)
#pragma unroll
    for (int nt = 0; nt < 8; ++nt) acc[mt][nt] = zero4;

  for (int kb = 0; kb < D_IN; kb += BK) {
#pragma unroll
    for (int it = 0; it < 8; ++it) {
      int idx = it * 256 + tid;
      int r = idx >> 4, c4 = idx & 15;
      int gm = row0 + r;
      if (gm >= N_NODES) gm = N_NODES - 1;
      float4 v = *(const float4*)(x + (size_t)gm * D_IN + kb + c4 * 4);
      u16x4 o;
      o.x = f2bf(v.x); o.y = f2bf(v.y); o.z = f2bf(v.z); o.w = f2bf(v.w);
      *(u16x4*)(lds_x + r * 72 + c4 * 4) = o;
    }
#pragma unroll
    for (int it = 0; it < 4; ++it) {
      int idx = it * 256 + tid;
      int n = idx >> 3, c8 = idx & 7;
      uint4 v = *(const uint4*)(w1b + n * 512 + kb + c8 * 8);
      *(uint4*)(lds_w + n * 72 + c8 * 8) = v;
    }
    __syncthreads();
#pragma unroll
    for (int kk = 0; kk < BK; kk += 32) {
      bf16x8 a[2], b[8];
#pragma unroll
      for (int mt = 0; mt < 2; ++mt)
        a[mt] = __builtin_bit_cast(bf16x8, *(const u16x8*)(lds_x + (wv * 32 + mt * 16 + fr) * 72 + kk + kq));
#pragma unroll
      for (int nt = 0; nt < 8; ++nt)
        b[nt] = __builtin_bit_cast(bf16x8, *(const u16x8*)(lds_w + (nt * 16 + fr) * 72 + kk + kq));
#pragma unroll
      for (int mt = 0; mt < 2; ++mt)
#pragma unroll
        for (int nt = 0; nt < 8; ++nt)
          acc[mt][nt] = __builtin_amdgcn_mfma_f32_16x16x32_bf16(a[mt], b[nt], acc[mt][nt], 0, 0, 0);
    }
    __syncthreads();
  }

  float b1v[8], b2v[8];
#pragma unroll
  for (int nt = 0; nt < 8; ++nt) {
    b1v[nt] = bias1[nt * 16 + fr];
    b2v[nt] = bias2[nt * 16 + fr];
  }
  float hr[2][8][4];
#pragma unroll
  for (int mt = 0; mt < 2; ++mt)
#pragma unroll
    for (int nt = 0; nt < 8; ++nt)
#pragma unroll
      for (int r = 0; r < 4; ++r) {
        int rl = wv * 32 + mt * 16 + rq + r;
        int cl = nt * 16 + fr;
        float h = acc[mt][nt][r] + b1v[nt];
        h = h > 0.f ? h : 0.f;
        hr[mt][nt][r] = h;
        lds_h[rl * 136 + cl] = f2bf(h);
      }
  __syncthreads();

  f32x4 acc2[2][8];
#pragma unroll
  for (int mt = 0; mt < 2; ++mt)
#pragma unroll
    for (int nt = 0; nt < 8; ++nt) acc2[mt][nt] = zero4;
#pragma unroll
  for (int kk = 0; kk < 128; kk += 32) {
    bf16x8 a[2], b[8];
#pragma unroll
    for (int mt = 0; mt < 2; ++mt)
      a[mt] = __builtin_bit_cast(bf16x8, *(const u16x8*)(lds_h + (wv * 32 + mt * 16 + fr) * 136 + kk + kq));
#pragma unroll
    for (int nt = 0; nt < 8; ++nt)
      b[nt] = __builtin_bit_cast(bf16x8, *(const u16x8*)(lds_w2 + (nt * 16 + fr) * 136 + kk + kq));
#pragma unroll
    for (int mt = 0; mt < 2; ++mt)
#pragma unroll
      for (int nt = 0; nt < 8; ++nt)
        acc2[mt][nt] = __builtin_amdgcn_mfma_f32_16x16x32_bf16(a[mt], b[nt], acc2[mt][nt], 0, 0, 0);
  }
  __syncthreads();

#pragma unroll
  for (int mt = 0; mt < 2; ++mt)
#pragma unroll
    for (int nt = 0; nt < 8; ++nt)
#pragma unroll
      for (int r = 0; r < 4; ++r) {
        int rl = wv * 32 + mt * 16 + rq + r;
        int cl = nt * 16 + fr;
        float t2 = acc2[mt][nt][r] + b2v[nt];
        t2 = t2 > 0.f ? t2 : 0.f;
        lds_h[rl * 136 + cl] = f2bf(hr[mt][nt][r] + t2);
      }
  __syncthreads();

  if (tid < 128) {
    int m = tid;
    int gm = row0 + m;
    if (gm < N_NODES) {
      float a0 = 0.f, a1 = 0.f, a2 = 0.f;
#pragma unroll 8
      for (int c = 0; c < 128; ++c) {
        float hv = bf2f(lds_h[m * 136 + c]);
        a0 += hv * lds_w3[c];
        a1 += hv * lds_w3[128 + c];
        a2 += hv * lds_w3[256 + c];
      }
      float z0 = a0 + b3[0], z1 = a1 + b3[1], z2 = a2 + b3[2];
      float di = dinv[gm];
      h0[gm] = make_float4(z0, z1, z2, 0.f);
      zt[gm] = make_float4(di * z0, di * z1, di * z2, 0.f);
    }
  }
}

// ---------------- one APPNP iteration ----------------
__global__ void k_iter(const float4* __restrict__ ztin, float4* __restrict__ ztout,
                       const int* __restrict__ row_start, const unsigned* __restrict__ csr_col,
                       const float* __restrict__ dinv, const float4* __restrict__ h0) {
  int i = blockIdx.x * 256 + threadIdx.x;
  if (i >= N_NODES) return;
  float4 self = ztin[i];
  float sx = self.x, sy = self.y, sz = self.z;
  int r0 = row_start[i], r1 = row_start[i + 1];
  int j = r0;
  for (; j + 1 < r1; j += 2) {
    int c0 = csr_col[j], c1 = csr_col[j + 1];
    float4 v0 = ztin[c0];
    float4 v1 = ztin[c1];
    sx += v0.x + v1.x; sy += v0.y + v1.y; sz += v0.z + v1.z;
  }
  if (j < r1) {
    float4 v = ztin[csr_col[j]];
    sx += v.x; sy += v.y; sz += v.z;
  }
  float di = dinv[i];
  float4 h = h0[i];
  float zx = (1.f - ALPHA) * di * sx + ALPHA * h.x;
  float zy = (1.f - ALPHA) * di * sy + ALPHA * h.y;
  float zz = (1.f - ALPHA) * di * sz + ALPHA * h.z;
  ztout[i] = make_float4(di * zx, di * zy, di * zz, 0.f);
}

// ---------------- final iteration + log_softmax ----------------
__global__ void k_final(const float4* __restrict__ ztin,
                        const int* __restrict__ row_start, const unsigned* __restrict__ csr_col,
                        const float* __restrict__ dinv, const float4* __restrict__ h0,
                        float* __restrict__ out) {
  int i = blockIdx.x * 256 + threadIdx.x;
  if (i >= N_NODES) return;
  float4 self = ztin[i];
  float sx = self.x, sy = self.y, sz = self.z;
  int r0 = row_start[i], r1 = row_start[i + 1];
  int j = r0;
  for (; j + 1 < r1; j += 2) {
    int c0 = csr_col[j], c1 = csr_col[j + 1];
    float4 v0 = ztin[c0];
    float4 v1 = ztin[c1];
    sx += v0.x + v1.x; sy += v0.y + v1.y; sz += v0.z + v1.z;
  }
  if (j < r1) {
    float4 v = ztin[csr_col[j]];
    sx += v.x; sy += v.y; sz += v.z;
  }
  float di = dinv[i];
  float4 h = h0[i];
  float zx = (1.f - ALPHA) * di * sx + ALPHA * h.x;
  float zy = (1.f - ALPHA) * di * sy + ALPHA * h.y;
  float zz = (1.f - ALPHA) * di * sz + ALPHA * h.z;
  float mx = fmaxf(zx, fmaxf(zy, zz));
  float l = logf(expf(zx - mx) + expf(zy - mx) + expf(zz - mx));
  out[i * 3 + 0] = zx - mx - l;
  out[i * 3 + 1] = zy - mx - l;
  out[i * 3 + 2] = zz - mx - l;
}

extern "C" void kernel_launch(void* const* d_in, const int* in_sizes, int n_in,
                              void* d_out, int out_size, void* d_ws, size_t ws_size,
                              hipStream_t stream) {
  const float* x   = (const float*)d_in[0];
  const int*   ei  = (const int*)d_in[1];
  const float* w1  = (const float*)d_in[2];
  const float* b1  = (const float*)d_in[3];
  const float* g1  = (const float*)d_in[4];
  const float* be1 = (const float*)d_in[5];
  const float* m1  = (const float*)d_in[6];
  const float* v1  = (const float*)d_in[7];
  const float* w2  = (const float*)d_in[8];
  const float* b2  = (const float*)d_in[9];
  const float* g2  = (const float*)d_in[10];
  const float* be2 = (const float*)d_in[11];
  const float* m2  = (const float*)d_in[12];
  const float* v2  = (const float*)d_in[13];
  const float* w3  = (const float*)d_in[14];
  const float* b3  = (const float*)d_in[15];

  const int E = in_sizes[1] / 2;
  const int* srcA = ei;
  const int* dstA = ei + E;

  char* w = (char*)d_ws;
  size_t off = 0;
  auto alloc = [&](size_t bytes) -> void* {
    void* p = w + off;
    off = (off + bytes + 255) & ~(size_t)255;
    return p;
  };
  unsigned short* w1b   = (unsigned short*)alloc(65536 * 2);
  unsigned short* w2b   = (unsigned short*)alloc(16384 * 2);
  float* bias1          = (float*)alloc(128 * 4);
  float* bias2          = (float*)alloc(128 * 4);
  int*   deg            = (int*)alloc((size_t)N_NODES * 4);
  int*   row_start      = (int*)alloc(((size_t)N_NODES + 1) * 4);
  float* dinv           = (float*)alloc((size_t)N_NODES * 4);
  int*   bsum           = (int*)alloc(512 * 4);
  int*   bcur           = (int*)alloc((size_t)NBUCKET * 4);
  int*   xcd_next       = (int*)alloc(8 * 4);
  float4* h0            = (float4*)alloc((size_t)N_NODES * 16);
  float4* ztA           = (float4*)alloc((size_t)N_NODES * 16);
  float4* ztB           = (float4*)alloc((size_t)N_NODES * 16);
  unsigned* csr_col     = (unsigned*)alloc((size_t)E * 4);

  const int NB = (N_NODES + 255) / 256;        // 391
  const int EB = (E + 255) / 256;

  k_prep<<<(82176 + N_NODES + NBUCKET + 8 + 255) / 256, 256, 0, stream>>>(
      w1, b1, g1, be1, m1, v1, w2, b2, g2, be2, m2, v2, w1b, w2b, bias1, bias2, deg, bcur, xcd_next);
  k_degree<<<EB, 256, 0, stream>>>(dstA, E, deg);
  k_scan1<<<NB, 256, 0, stream>>>(deg, bsum);
  k_scan2<<<1, 256, 0, stream>>>(bsum);
  k_scan3<<<NB, 256, 0, stream>>>(deg, bsum, row_start, dinv, E);
  k_bucketA<<<1024, 256, 0, stream>>>(srcA, dstA, E, row_start, bcur, csr_col, xcd_next);
  k_bucketB<<<NBUCKET, 256, 0, stream>>>(row_start, csr_col);
  k_mlp<<<(N_NODES + M_TILE - 1) / M_TILE, 256, 0, stream>>>(
      x, w1b, w2b, bias1, bias2, w3, b3, dinv, h0, ztA);

  const float4* zin = ztA;
  float4* zout = ztB;
  for (int k = 0; k < 9; ++k) {
    k_iter<<<NB, 256, 0, stream>>>(zin, zout, row_start, csr_col, dinv, h0);
    const float4* t = zout;
    zout = (float4*)zin;
    zin = t;
  }
  k_final<<<NB, 256, 0, stream>>>(zin, row_start, csr_col, dinv, h0, (float*)d_out);
}

// Round 4
// 800.090 us; speedup vs baseline: 1.4964x; 1.4964x over previous
//
#include <hip/hip_runtime.h>
#include <cstdint>
#include <cstddef>

#define N_NODES 100000
#define D_IN 512
#define ALPHA 0.1f
#define EPS_BN 1e-5f
#define M_TILE 128
#define BK 64

// ---- CSR build: 256-node bins, tile-staged counting sort ----
#define CBITS 8
#define CNODES 256
#define NCBIN 391            // ceil(100000/256)
#define TILE 8192
#define EPT 32               // edges per thread (256 threads * 32 = 8192)
#define BCAP 10240           // binB LDS sort capacity (mean 8192 + 22 sigma)

typedef float f32x4 __attribute__((ext_vector_type(4)));
typedef __bf16 bf16x8 __attribute__((ext_vector_type(8)));
typedef unsigned short u16x8 __attribute__((ext_vector_type(8)));
typedef unsigned short u16x4 __attribute__((ext_vector_type(4)));

__device__ __forceinline__ unsigned short f2bf(float f) {
  unsigned u = __float_as_uint(f);
  u += 0x7fffu + ((u >> 16) & 1u);   // RNE
  return (unsigned short)(u >> 16);
}
__device__ __forceinline__ float bf2f(unsigned short h) {
  return __uint_as_float(((unsigned)h) << 16);
}

// ---------------- prep: fold BN into weights (bf16) + biases, zero deg + bin cursors ----------------
__global__ void k_prep(const float* __restrict__ w1, const float* __restrict__ b1,
                       const float* __restrict__ g1, const float* __restrict__ be1,
                       const float* __restrict__ m1, const float* __restrict__ v1,
                       const float* __restrict__ w2, const float* __restrict__ b2,
                       const float* __restrict__ g2, const float* __restrict__ be2,
                       const float* __restrict__ m2, const float* __restrict__ v2,
                       unsigned short* __restrict__ w1b, unsigned short* __restrict__ w2b,
                       float* __restrict__ bias1, float* __restrict__ bias2,
                       int* __restrict__ deg, int* __restrict__ bincur) {
  int idx = blockIdx.x * 256 + threadIdx.x;
  if (idx < 65536) {                       // w1: [128][512], scale row n by s1[n]
    int n = idx >> 9;
    float s = g1[n] * rsqrtf(v1[n] + EPS_BN);
    w1b[idx] = f2bf(w1[idx] * s);
  } else if (idx < 81920) {                // w2: [128][128]
    int i = idx - 65536;
    int n = i >> 7;
    float s = g2[n] * rsqrtf(v2[n] + EPS_BN);
    w2b[i] = f2bf(w2[i] * s);
  } else if (idx < 82048) {
    int c = idx - 81920;
    float s = g1[c] * rsqrtf(v1[c] + EPS_BN);
    bias1[c] = (b1[c] - m1[c]) * s + be1[c];
  } else if (idx < 82176) {
    int c = idx - 82048;
    float s = g2[c] * rsqrtf(v2[c] + EPS_BN);
    bias2[c] = (b2[c] - m2[c]) * s + be2[c];
  }
  int di = idx - 82176;
  if (di >= 0 && di < N_NODES) deg[di] = 0;
  int bi = di - N_NODES;
  if (bi >= 0 && bi < NCBIN) bincur[bi] = 0;
}

// ---------------- in-degree histogram ----------------
__global__ void k_degree(const int* __restrict__ dst, int E, int* __restrict__ deg) {
  int e = blockIdx.x * 256 + threadIdx.x;
  if (e < E) atomicAdd(&deg[dst[e]], 1);
}

// ---------------- 3-level exclusive scan of deg -> row_start ----------------
__global__ void k_scan1(const int* __restrict__ deg, int* __restrict__ bsum) {
  __shared__ int red[256];
  int t = threadIdx.x;
  int i = blockIdx.x * 256 + t;
  red[t] = (i < N_NODES) ? deg[i] : 0;
  __syncthreads();
  for (int off = 128; off > 0; off >>= 1) {
    if (t < off) red[t] += red[t + off];
    __syncthreads();
  }
  if (t == 0) bsum[blockIdx.x] = red[0];
}

#define NB_SCAN 391
__global__ void k_scan2(int* __restrict__ bsum) {
  __shared__ int s[448];
  int t = threadIdx.x;
  for (int i = t; i < 448; i += 256) s[i] = (i < NB_SCAN) ? bsum[i] : 0;
  __syncthreads();
  if (t < 64) {
    int base = t * 7;
    int vals[7];
    int sum = 0;
#pragma unroll
    for (int j = 0; j < 7; ++j) { vals[j] = s[base + j]; sum += vals[j]; }
    int x = sum;
#pragma unroll
    for (int off = 1; off < 64; off <<= 1) {
      int y = __shfl_up(x, off, 64);
      if (t >= off) x += y;
    }
    int run = x - sum;   // exclusive prefix of lane sums
#pragma unroll
    for (int j = 0; j < 7; ++j) { int tmp = vals[j]; s[base + j] = run; run += tmp; }
  }
  __syncthreads();
  for (int i = t; i < NB_SCAN; i += 256) bsum[i] = s[i];
}

__global__ void k_scan3(const int* __restrict__ deg, const int* __restrict__ bsum,
                        int* __restrict__ row_start, float* __restrict__ dinv, int E) {
  __shared__ int sb[2][256];
  int t = threadIdx.x;
  int i = blockIdx.x * 256 + t;
  int d = (i < N_NODES) ? deg[i] : 0;
  sb[0][t] = d;
  __syncthreads();
  int cur = 0;
#pragma unroll
  for (int off = 1; off < 256; off <<= 1) {
    int val = sb[cur][t] + ((t >= off) ? sb[cur][t - off] : 0);
    sb[cur ^ 1][t] = val;
    __syncthreads();
    cur ^= 1;
  }
  int incl = sb[cur][t];
  int ex = incl - d;
  if (i < N_NODES) {
    int rs = bsum[blockIdx.x] + ex;
    row_start[i] = rs;
    dinv[i] = rsqrtf((float)(d + 1));   // +1 self-loop
  }
  if (i == N_NODES) row_start[N_NODES] = E;
}

// ---------------- pass A: tile-staged bin scatter (write-combined) ----------------
// Each block takes one 8192-edge tile, classifies into 391 bins of 256 dst nodes,
// stages the tile bin-sorted in LDS, then copies out linearly -> contiguous ~21-entry
// runs per bin region in csr_col. One global atomicAdd per (tile, bin).
__global__ __launch_bounds__(256) void k_binA(const int* __restrict__ src,
                                              const int* __restrict__ dst, int E,
                                              const int* __restrict__ row_start,
                                              int* __restrict__ bincur,
                                              unsigned* __restrict__ csr_col) {
  __shared__ unsigned stage[TILE];
  __shared__ int cnt[NCBIN];
  __shared__ int loff[NCBIN + 1];
  __shared__ int goff[NCBIN];
  __shared__ int rs0s[NCBIN];
  __shared__ int sc[2][256];
  const int tid = threadIdx.x;

  // precompute bin region bases (row_start at bin's first node)
  for (int i = tid; i < NCBIN; i += 256) rs0s[i] = row_start[i << CBITS];
  for (int i = tid; i < NCBIN; i += 256) cnt[i] = 0;
  __syncthreads();

  const int e0 = blockIdx.x * TILE;
  const int n = min(TILE, E - e0);

  unsigned pk[EPT];
  int bp[EPT];
#pragma unroll
  for (int i = 0; i < EPT; ++i) {
    int o = i * 256 + tid;
    if (o < n) {
      int e = e0 + o;
      int d = dst[e];
      int s = src[e];
      int b = d >> CBITS;
      pk[i] = (unsigned)s | ((unsigned)(d & (CNODES - 1)) << 17);
      int p = atomicAdd(&cnt[b], 1);
      bp[i] = b | (p << 9);             // b: 9 bits, p: <= 13 bits
    } else bp[i] = -1;
  }
  __syncthreads();

  // exclusive scan of cnt[391] (pairs -> Hillis-Steele over 256)
  int c0 = (2 * tid     < NCBIN) ? cnt[2 * tid]     : 0;
  int c1 = (2 * tid + 1 < NCBIN) ? cnt[2 * tid + 1] : 0;
  sc[0][tid] = c0 + c1;
  __syncthreads();
  int cur = 0;
#pragma unroll
  for (int off = 1; off < 256; off <<= 1) {
    sc[cur ^ 1][tid] = sc[cur][tid] + ((tid >= off) ? sc[cur][tid - off] : 0);
    __syncthreads();
    cur ^= 1;
  }
  int ex = sc[cur][tid] - (c0 + c1);
  if (2 * tid < NCBIN) loff[2 * tid] = ex;
  if (2 * tid + 1 < NCBIN) loff[2 * tid + 1] = ex + c0;
  if (tid == 255) loff[NCBIN] = sc[cur][255];
  __syncthreads();
  // reserve global space per bin
  for (int i = tid; i < NCBIN; i += 256)
    if (cnt[i] > 0) goff[i] = atomicAdd(&bincur[i], cnt[i]);
  __syncthreads();

  // scatter into LDS stage (bin-sorted within tile)
#pragma unroll
  for (int i = 0; i < EPT; ++i) {
    if (bp[i] >= 0) {
      int b = bp[i] & 511;
      int p = bp[i] >> 9;
      stage[loff[b] + p] = pk[i];
    }
  }
  __syncthreads();

  // linear copy-out: contiguous runs per bin
  for (int i = tid; i < n; i += 256) {
    int lo = 0, hi = NCBIN;
    while (hi - lo > 1) { int mid = (lo + hi) >> 1; if (loff[mid] <= i) lo = mid; else hi = mid; }
    int b = lo;
    int destp = rs0s[b] + goff[b] + (i - loff[b]);
    csr_col[destp] = stage[i];
  }
}

// ---------------- pass B: per-bin in-place sort via LDS cursors ----------------
__global__ __launch_bounds__(256) void k_binB(const int* __restrict__ row_start,
                                              unsigned* __restrict__ csr_col) {
  __shared__ unsigned sortbuf[BCAP];
  __shared__ int lcur[CNODES];
  int b = blockIdx.x;
  int t = threadIdx.x;
  int node0 = b << CBITS;
  int nodes = min(CNODES, N_NODES - node0);
  int rs0 = row_start[node0];
  int rsE = row_start[min(node0 + CNODES, N_NODES)];
  int cnt = rsE - rs0;
  if (t < nodes) lcur[t] = row_start[node0 + t] - rs0;
  __syncthreads();
  for (int i = t; i < cnt; i += 256) {
    unsigned v = csr_col[rs0 + i];
    int ld = (int)(v >> 17);
    int p = atomicAdd(&lcur[ld], 1);
    if (p < BCAP) sortbuf[p] = v & 0x1FFFFu;
  }
  __syncthreads();
  for (int i = t; i < cnt; i += 256) csr_col[rs0 + i] = sortbuf[i];
}

// ---------------- fused MLP: x -> h0[N,4], zt0 = dinv*h0 ----------------
__global__ __launch_bounds__(256, 2) void k_mlp(
    const float* __restrict__ x, const unsigned short* __restrict__ w1b,
    const unsigned short* __restrict__ w2b, const float* __restrict__ bias1,
    const float* __restrict__ bias2, const float* __restrict__ w3,
    const float* __restrict__ b3, const float* __restrict__ dinv,
    float4* __restrict__ h0, float4* __restrict__ zt) {
  __shared__ unsigned short arena[35840];
  __shared__ float lds_w3[384];
  unsigned short* lds_x = arena;
  unsigned short* lds_w = arena + 9216;
  unsigned short* lds_h = arena;
  unsigned short* lds_w2 = arena + 18432;

  const int tid = threadIdx.x;
  const int lane = tid & 63;
  const int wv = tid >> 6;
  const int fr = lane & 15;
  const int kq = (lane >> 4) * 8;
  const int rq = (lane >> 4) * 4;
  const int row0 = blockIdx.x * M_TILE;

  for (int i = tid; i < 384; i += 256) lds_w3[i] = w3[i];

#pragma unroll
  for (int it = 0; it < 8; ++it) {
    int idx = it * 256 + tid;
    int n = idx >> 4, c8 = idx & 15;
    uint4 v = *(const uint4*)(w2b + n * 128 + c8 * 8);
    *(uint4*)(lds_w2 + n * 136 + c8 * 8) = v;
  }

  f32x4 zero4 = {0.f, 0.f, 0.f, 0.f};
  f32x4 acc[2][8];
#pragma unroll
  for (int mt = 0; mt < 2; ++mt)
#pragma unroll
    for (int nt = 0; nt < 8; ++nt) acc[mt][nt] = zero4;

  for (int kb = 0; kb < D_IN; kb += BK) {
#pragma unroll
    for (int it = 0; it < 8; ++it) {
      int idx = it * 256 + tid;
      int r = idx >> 4, c4 = idx & 15;
      int gm = row0 + r;
      if (gm >= N_NODES) gm = N_NODES - 1;
      float4 v = *(const float4*)(x + (size_t)gm * D_IN + kb + c4 * 4);
      u16x4 o;
      o.x = f2bf(v.x); o.y = f2bf(v.y); o.z = f2bf(v.z); o.w = f2bf(v.w);
      *(u16x4*)(lds_x + r * 72 + c4 * 4) = o;
    }
#pragma unroll
    for (int it = 0; it < 4; ++it) {
      int idx = it * 256 + tid;
      int n = idx >> 3, c8 = idx & 7;
      uint4 v = *(const uint4*)(w1b + n * 512 + kb + c8 * 8);
      *(uint4*)(lds_w + n * 72 + c8 * 8) = v;
    }
    __syncthreads();
#pragma unroll
    for (int kk = 0; kk < BK; kk += 32) {
      bf16x8 a[2], b[8];
#pragma unroll
      for (int mt = 0; mt < 2; ++mt)
        a[mt] = __builtin_bit_cast(bf16x8, *(const u16x8*)(lds_x + (wv * 32 + mt * 16 + fr) * 72 + kk + kq));
#pragma unroll
      for (int nt = 0; nt < 8; ++nt)
        b[nt] = __builtin_bit_cast(bf16x8, *(const u16x8*)(lds_w + (nt * 16 + fr) * 72 + kk + kq));
#pragma unroll
      for (int mt = 0; mt < 2; ++mt)
#pragma unroll
        for (int nt = 0; nt < 8; ++nt)
          acc[mt][nt] = __builtin_amdgcn_mfma_f32_16x16x32_bf16(a[mt], b[nt], acc[mt][nt], 0, 0, 0);
    }
    __syncthreads();
  }

  float b1v[8], b2v[8];
#pragma unroll
  for (int nt = 0; nt < 8; ++nt) {
    b1v[nt] = bias1[nt * 16 + fr];
    b2v[nt] = bias2[nt * 16 + fr];
  }
  float hr[2][8][4];
#pragma unroll
  for (int mt = 0; mt < 2; ++mt)
#pragma unroll
    for (int nt = 0; nt < 8; ++nt)
#pragma unroll
      for (int r = 0; r < 4; ++r) {
        int rl = wv * 32 + mt * 16 + rq + r;
        int cl = nt * 16 + fr;
        float h = acc[mt][nt][r] + b1v[nt];
        h = h > 0.f ? h : 0.f;
        hr[mt][nt][r] = h;
        lds_h[rl * 136 + cl] = f2bf(h);
      }
  __syncthreads();

  f32x4 acc2[2][8];
#pragma unroll
  for (int mt = 0; mt < 2; ++mt)
#pragma unroll
    for (int nt = 0; nt < 8; ++nt) acc2[mt][nt] = zero4;
#pragma unroll
  for (int kk = 0; kk < 128; kk += 32) {
    bf16x8 a[2], b[8];
#pragma unroll
    for (int mt = 0; mt < 2; ++mt)
      a[mt] = __builtin_bit_cast(bf16x8, *(const u16x8*)(lds_h + (wv * 32 + mt * 16 + fr) * 136 + kk + kq));
#pragma unroll
    for (int nt = 0; nt < 8; ++nt)
      b[nt] = __builtin_bit_cast(bf16x8, *(const u16x8*)(lds_w2 + (nt * 16 + fr) * 136 + kk + kq));
#pragma unroll
    for (int mt = 0; mt < 2; ++mt)
#pragma unroll
      for (int nt = 0; nt < 8; ++nt)
        acc2[mt][nt] = __builtin_amdgcn_mfma_f32_16x16x32_bf16(a[mt], b[nt], acc2[mt][nt], 0, 0, 0);
  }
  __syncthreads();

#pragma unroll
  for (int mt = 0; mt < 2; ++mt)
#pragma unroll
    for (int nt = 0; nt < 8; ++nt)
#pragma unroll
      for (int r = 0; r < 4; ++r) {
        int rl = wv * 32 + mt * 16 + rq + r;
        int cl = nt * 16 + fr;
        float t2 = acc2[mt][nt][r] + b2v[nt];
        t2 = t2 > 0.f ? t2 : 0.f;
        lds_h[rl * 136 + cl] = f2bf(hr[mt][nt][r] + t2);
      }
  __syncthreads();

  if (tid < 128) {
    int m = tid;
    int gm = row0 + m;
    if (gm < N_NODES) {
      float a0 = 0.f, a1 = 0.f, a2 = 0.f;
#pragma unroll 8
      for (int c = 0; c < 128; ++c) {
        float hv = bf2f(lds_h[m * 136 + c]);
        a0 += hv * lds_w3[c];
        a1 += hv * lds_w3[128 + c];
        a2 += hv * lds_w3[256 + c];
      }
      float z0 = a0 + b3[0], z1 = a1 + b3[1], z2 = a2 + b3[2];
      float di = dinv[gm];
      h0[gm] = make_float4(z0, z1, z2, 0.f);
      zt[gm] = make_float4(di * z0, di * z1, di * z2, 0.f);
    }
  }
}

// ---------------- one APPNP iteration ----------------
__global__ void k_iter(const float4* __restrict__ ztin, float4* __restrict__ ztout,
                       const int* __restrict__ row_start, const unsigned* __restrict__ csr_col,
                       const float* __restrict__ dinv, const float4* __restrict__ h0) {
  int i = blockIdx.x * 256 + threadIdx.x;
  if (i >= N_NODES) return;
  float4 self = ztin[i];
  float sx = self.x, sy = self.y, sz = self.z;
  int r0 = row_start[i], r1 = row_start[i + 1];
  int j = r0;
  for (; j + 1 < r1; j += 2) {
    int c0 = csr_col[j], c1 = csr_col[j + 1];
    float4 v0 = ztin[c0];
    float4 v1 = ztin[c1];
    sx += v0.x + v1.x; sy += v0.y + v1.y; sz += v0.z + v1.z;
  }
  if (j < r1) {
    float4 v = ztin[csr_col[j]];
    sx += v.x; sy += v.y; sz += v.z;
  }
  float di = dinv[i];
  float4 h = h0[i];
  float zx = (1.f - ALPHA) * di * sx + ALPHA * h.x;
  float zy = (1.f - ALPHA) * di * sy + ALPHA * h.y;
  float zz = (1.f - ALPHA) * di * sz + ALPHA * h.z;
  ztout[i] = make_float4(di * zx, di * zy, di * zz, 0.f);
}

// ---------------- final iteration + log_softmax ----------------
__global__ void k_final(const float4* __restrict__ ztin,
                        const int* __restrict__ row_start, const unsigned* __restrict__ csr_col,
                        const float* __restrict__ dinv, const float4* __restrict__ h0,
                        float* __restrict__ out) {
  int i = blockIdx.x * 256 + threadIdx.x;
  if (i >= N_NODES) return;
  float4 self = ztin[i];
  float sx = self.x, sy = self.y, sz = self.z;
  int r0 = row_start[i], r1 = row_start[i + 1];
  int j = r0;
  for (; j + 1 < r1; j += 2) {
    int c0 = csr_col[j], c1 = csr_col[j + 1];
    float4 v0 = ztin[c0];
    float4 v1 = ztin[c1];
    sx += v0.x + v1.x; sy += v0.y + v1.y; sz += v0.z + v1.z;
  }
  if (j < r1) {
    float4 v = ztin[csr_col[j]];
    sx += v.x; sy += v.y; sz += v.z;
  }
  float di = dinv[i];
  float4 h = h0[i];
  float zx = (1.f - ALPHA) * di * sx + ALPHA * h.x;
  float zy = (1.f - ALPHA) * di * sy + ALPHA * h.y;
  float zz = (1.f - ALPHA) * di * sz + ALPHA * h.z;
  float mx = fmaxf(zx, fmaxf(zy, zz));
  float l = logf(expf(zx - mx) + expf(zy - mx) + expf(zz - mx));
  out[i * 3 + 0] = zx - mx - l;
  out[i * 3 + 1] = zy - mx - l;
  out[i * 3 + 2] = zz - mx - l;
}

extern "C" void kernel_launch(void* const* d_in, const int* in_sizes, int n_in,
                              void* d_out, int out_size, void* d_ws, size_t ws_size,
                              hipStream_t stream) {
  const float* x   = (const float*)d_in[0];
  const int*   ei  = (const int*)d_in[1];
  const float* w1  = (const float*)d_in[2];
  const float* b1  = (const float*)d_in[3];
  const float* g1  = (const float*)d_in[4];
  const float* be1 = (const float*)d_in[5];
  const float* m1  = (const float*)d_in[6];
  const float* v1  = (const float*)d_in[7];
  const float* w2  = (const float*)d_in[8];
  const float* b2  = (const float*)d_in[9];
  const float* g2  = (const float*)d_in[10];
  const float* be2 = (const float*)d_in[11];
  const float* m2  = (const float*)d_in[12];
  const float* v2  = (const float*)d_in[13];
  const float* w3  = (const float*)d_in[14];
  const float* b3  = (const float*)d_in[15];

  const int E = in_sizes[1] / 2;
  const int* srcA = ei;
  const int* dstA = ei + E;

  char* w = (char*)d_ws;
  size_t off = 0;
  auto alloc = [&](size_t bytes) -> void* {
    void* p = w + off;
    off = (off + bytes + 255) & ~(size_t)255;
    return p;
  };
  unsigned short* w1b   = (unsigned short*)alloc(65536 * 2);
  unsigned short* w2b   = (unsigned short*)alloc(16384 * 2);
  float* bias1          = (float*)alloc(128 * 4);
  float* bias2          = (float*)alloc(128 * 4);
  int*   deg            = (int*)alloc((size_t)N_NODES * 4);
  int*   row_start      = (int*)alloc(((size_t)N_NODES + 1) * 4);
  float* dinv           = (float*)alloc((size_t)N_NODES * 4);
  int*   bsum           = (int*)alloc(512 * 4);
  int*   bincur         = (int*)alloc((size_t)NCBIN * 4);
  float4* h0            = (float4*)alloc((size_t)N_NODES * 16);
  float4* ztA           = (float4*)alloc((size_t)N_NODES * 16);
  float4* ztB           = (float4*)alloc((size_t)N_NODES * 16);
  unsigned* csr_col     = (unsigned*)alloc((size_t)E * 4);

  const int NB = (N_NODES + 255) / 256;        // 391
  const int EB = (E + 255) / 256;
  const int NTILE = (E + TILE - 1) / TILE;     // 391 for E=3.2M

  k_prep<<<(82176 + N_NODES + NCBIN + 255) / 256, 256, 0, stream>>>(
      w1, b1, g1, be1, m1, v1, w2, b2, g2, be2, m2, v2, w1b, w2b, bias1, bias2, deg, bincur);
  k_degree<<<EB, 256, 0, stream>>>(dstA, E, deg);
  k_scan1<<<NB, 256, 0, stream>>>(deg, bsum);
  k_scan2<<<1, 256, 0, stream>>>(bsum);
  k_scan3<<<NB, 256, 0, stream>>>(deg, bsum, row_start, dinv, E);
  k_binA<<<NTILE, 256, 0, stream>>>(srcA, dstA, E, row_start, bincur, csr_col);
  k_binB<<<NCBIN, 256, 0, stream>>>(row_start, csr_col);
  k_mlp<<<(N_NODES + M_TILE - 1) / M_TILE, 256, 0, stream>>>(
      x, w1b, w2b, bias1, bias2, w3, b3, dinv, h0, ztA);

  const float4* zin = ztA;
  float4* zout = ztB;
  for (int k = 0; k < 9; ++k) {
    k_iter<<<NB, 256, 0, stream>>>(zin, zout, row_start, csr_col, dinv, h0);
    const float4* t = zout;
    zout = (float4*)zin;
    zin = t;
  }
  k_final<<<NB, 256, 0, stream>>>(zin, row_start, csr_col, dinv, h0, (float*)d_out);
}

// Round 5
// 679.269 us; speedup vs baseline: 1.7626x; 1.1779x over previous
//
#include <hip/hip_runtime.h>
#include <cstdint>
#include <cstddef>

#define N_NODES 100000
#define D_IN 512
#define ALPHA 0.1f
#define EPS_BN 1e-5f
#define M_TILE 128
#define BK 64

// ---- CSR build: 256-node bins, tile-staged counting sort ----
#define CBITS 8
#define CNODES 256
#define NCBIN 391            // ceil(100000/256)
#define TILE 8192
#define EPT 32               // edges per thread (256 threads * 32 = 8192)
#define BINCAP 9216          // per-bin fixed capacity (mean 8192 + 11 sigma)

typedef float f32x4 __attribute__((ext_vector_type(4)));
typedef __bf16 bf16x8 __attribute__((ext_vector_type(8)));
typedef unsigned short u16x8 __attribute__((ext_vector_type(8)));
typedef unsigned short u16x4 __attribute__((ext_vector_type(4)));

__device__ __forceinline__ unsigned short f2bf(float f) {
  unsigned u = __float_as_uint(f);
  u += 0x7fffu + ((u >> 16) & 1u);   // RNE
  return (unsigned short)(u >> 16);
}
__device__ __forceinline__ float bf2f(unsigned short h) {
  return __uint_as_float(((unsigned)h) << 16);
}

// ---------------- prep: fold BN into weights (bf16) + biases, zero bin cursors ----------------
__global__ void k_prep(const float* __restrict__ w1, const float* __restrict__ b1,
                       const float* __restrict__ g1, const float* __restrict__ be1,
                       const float* __restrict__ m1, const float* __restrict__ v1,
                       const float* __restrict__ w2, const float* __restrict__ b2,
                       const float* __restrict__ g2, const float* __restrict__ be2,
                       const float* __restrict__ m2, const float* __restrict__ v2,
                       unsigned short* __restrict__ w1b, unsigned short* __restrict__ w2b,
                       float* __restrict__ bias1, float* __restrict__ bias2,
                       int* __restrict__ bincur) {
  int idx = blockIdx.x * 256 + threadIdx.x;
  if (idx < 65536) {                       // w1: [128][512], scale row n by s1[n]
    int n = idx >> 9;
    float s = g1[n] * rsqrtf(v1[n] + EPS_BN);
    w1b[idx] = f2bf(w1[idx] * s);
  } else if (idx < 81920) {                // w2: [128][128]
    int i = idx - 65536;
    int n = i >> 7;
    float s = g2[n] * rsqrtf(v2[n] + EPS_BN);
    w2b[i] = f2bf(w2[i] * s);
  } else if (idx < 82048) {
    int c = idx - 81920;
    float s = g1[c] * rsqrtf(v1[c] + EPS_BN);
    bias1[c] = (b1[c] - m1[c]) * s + be1[c];
  } else if (idx < 82176) {
    int c = idx - 82048;
    float s = g2[c] * rsqrtf(v2[c] + EPS_BN);
    bias2[c] = (b2[c] - m2[c]) * s + be2[c];
  }
  int bi = idx - 82176;
  if (bi >= 0 && bi < NCBIN) bincur[bi] = 0;
}

// ---------------- 3-level exclusive scan of deg -> row_start ----------------
__global__ void k_scan1(const int* __restrict__ deg, int* __restrict__ bsum) {
  __shared__ int red[256];
  int t = threadIdx.x;
  int i = blockIdx.x * 256 + t;
  red[t] = (i < N_NODES) ? deg[i] : 0;
  __syncthreads();
  for (int off = 128; off > 0; off >>= 1) {
    if (t < off) red[t] += red[t + off];
    __syncthreads();
  }
  if (t == 0) bsum[blockIdx.x] = red[0];
}

#define NB_SCAN 391
__global__ void k_scan2(int* __restrict__ bsum) {
  __shared__ int s[448];
  int t = threadIdx.x;
  for (int i = t; i < 448; i += 256) s[i] = (i < NB_SCAN) ? bsum[i] : 0;
  __syncthreads();
  if (t < 64) {
    int base = t * 7;
    int vals[7];
    int sum = 0;
#pragma unroll
    for (int j = 0; j < 7; ++j) { vals[j] = s[base + j]; sum += vals[j]; }
    int x = sum;
#pragma unroll
    for (int off = 1; off < 64; off <<= 1) {
      int y = __shfl_up(x, off, 64);
      if (t >= off) x += y;
    }
    int run = x - sum;   // exclusive prefix of lane sums
#pragma unroll
    for (int j = 0; j < 7; ++j) { int tmp = vals[j]; s[base + j] = run; run += tmp; }
  }
  __syncthreads();
  for (int i = t; i < NB_SCAN; i += 256) bsum[i] = s[i];
}

__global__ void k_scan3(const int* __restrict__ deg, const int* __restrict__ bsum,
                        int* __restrict__ row_start, float* __restrict__ dinv, int E) {
  __shared__ int sb[2][256];
  int t = threadIdx.x;
  int i = blockIdx.x * 256 + t;
  int d = (i < N_NODES) ? deg[i] : 0;
  sb[0][t] = d;
  __syncthreads();
  int cur = 0;
#pragma unroll
  for (int off = 1; off < 256; off <<= 1) {
    int val = sb[cur][t] + ((t >= off) ? sb[cur][t - off] : 0);
    sb[cur ^ 1][t] = val;
    __syncthreads();
    cur ^= 1;
  }
  int incl = sb[cur][t];
  int ex = incl - d;
  if (i < N_NODES) {
    int rs = bsum[blockIdx.x] + ex;
    row_start[i] = rs;
    dinv[i] = rsqrtf((float)(d + 1));   // +1 self-loop
  }
  if (i == N_NODES) row_start[N_NODES] = E;
}

// ---------------- pass A: tile-staged bin scatter into fixed-capacity bin regions ----------------
// No deg/row_start dependency. Write-combined: per-tile LDS staging, contiguous ~21-entry
// runs per bin. One global atomicAdd per (tile, bin).
__global__ __launch_bounds__(256) void k_binA(const int* __restrict__ src,
                                              const int* __restrict__ dst, int E,
                                              int* __restrict__ bincur,
                                              unsigned* __restrict__ binned) {
  __shared__ unsigned stage[TILE];
  __shared__ int cnt[NCBIN];
  __shared__ int loff[NCBIN + 1];
  __shared__ int goff[NCBIN];
  __shared__ int sc[2][256];
  const int tid = threadIdx.x;

  for (int i = tid; i < NCBIN; i += 256) cnt[i] = 0;
  __syncthreads();

  const int e0 = blockIdx.x * TILE;
  const int n = min(TILE, E - e0);

  unsigned pk[EPT];
  int bp[EPT];
#pragma unroll
  for (int i = 0; i < EPT; ++i) {
    int o = i * 256 + tid;
    if (o < n) {
      int e = e0 + o;
      int d = dst[e];
      int s = src[e];
      int b = d >> CBITS;
      pk[i] = (unsigned)s | ((unsigned)(d & (CNODES - 1)) << 17);
      int p = atomicAdd(&cnt[b], 1);
      bp[i] = b | (p << 9);             // b: 9 bits, p: <= 13 bits
    } else bp[i] = -1;
  }
  __syncthreads();

  // exclusive scan of cnt[391] (pairs -> Hillis-Steele over 256)
  int c0 = (2 * tid     < NCBIN) ? cnt[2 * tid]     : 0;
  int c1 = (2 * tid + 1 < NCBIN) ? cnt[2 * tid + 1] : 0;
  sc[0][tid] = c0 + c1;
  __syncthreads();
  int cur = 0;
#pragma unroll
  for (int off = 1; off < 256; off <<= 1) {
    sc[cur ^ 1][tid] = sc[cur][tid] + ((tid >= off) ? sc[cur][tid - off] : 0);
    __syncthreads();
    cur ^= 1;
  }
  int ex = sc[cur][tid] - (c0 + c1);
  if (2 * tid < NCBIN) loff[2 * tid] = ex;
  if (2 * tid + 1 < NCBIN) loff[2 * tid + 1] = ex + c0;
  if (tid == 255) loff[NCBIN] = sc[cur][255];
  __syncthreads();
  // reserve global space per bin
  for (int i = tid; i < NCBIN; i += 256)
    if (cnt[i] > 0) goff[i] = atomicAdd(&bincur[i], cnt[i]);
  __syncthreads();

  // scatter into LDS stage (bin-sorted within tile)
#pragma unroll
  for (int i = 0; i < EPT; ++i) {
    if (bp[i] >= 0) {
      int b = bp[i] & 511;
      int p = bp[i] >> 9;
      stage[loff[b] + p] = pk[i];
    }
  }
  __syncthreads();

  // linear copy-out: contiguous runs per bin
  for (int i = tid; i < n; i += 256) {
    int lo = 0, hi = NCBIN;
    while (hi - lo > 1) { int mid = (lo + hi) >> 1; if (loff[mid] <= i) lo = mid; else hi = mid; }
    int b = lo;
    binned[(size_t)b * BINCAP + goff[b] + (i - loff[b])] = stage[i];
  }
}

// ---------------- pass B1: per-bin degree count (LDS atomics, coalesced deg write) ----------------
__global__ __launch_bounds__(256) void k_binB1(const unsigned* __restrict__ binned,
                                               const int* __restrict__ bincur,
                                               int* __restrict__ deg) {
  __shared__ int lcnt[CNODES];
  int b = blockIdx.x;
  int t = threadIdx.x;
  lcnt[t] = 0;
  __syncthreads();
  int cnt = bincur[b];
  const unsigned* bp = binned + (size_t)b * BINCAP;
  for (int i = t; i < cnt; i += 256) {
    unsigned v = bp[i];
    atomicAdd(&lcnt[v >> 17], 1);
  }
  __syncthreads();
  int node = (b << CBITS) + t;
  if (node < N_NODES) deg[node] = lcnt[t];
}

// ---------------- pass B2: per-bin LDS-cursor sort -> coalesced csr_col write ----------------
__global__ __launch_bounds__(256) void k_binB2(const unsigned* __restrict__ binned,
                                               const int* __restrict__ bincur,
                                               const int* __restrict__ row_start,
                                               unsigned* __restrict__ csr_col) {
  __shared__ unsigned sortbuf[BINCAP];
  __shared__ int lcur[CNODES];
  int b = blockIdx.x;
  int t = threadIdx.x;
  int node0 = b << CBITS;
  int nodes = min(CNODES, N_NODES - node0);
  int rs0 = row_start[node0];
  if (t < nodes) lcur[t] = row_start[node0 + t] - rs0;
  __syncthreads();
  int cnt = bincur[b];
  const unsigned* bp = binned + (size_t)b * BINCAP;
  for (int i = t; i < cnt; i += 256) {
    unsigned v = bp[i];
    int p = atomicAdd(&lcur[v >> 17], 1);
    sortbuf[p] = v & 0x1FFFFu;
  }
  __syncthreads();
  for (int i = t; i < cnt; i += 256) csr_col[rs0 + i] = sortbuf[i];
}

// ---------------- fused MLP: x -> h0[N,4], zt0 = dinv*h0 ----------------
__global__ __launch_bounds__(256, 2) void k_mlp(
    const float* __restrict__ x, const unsigned short* __restrict__ w1b,
    const unsigned short* __restrict__ w2b, const float* __restrict__ bias1,
    const float* __restrict__ bias2, const float* __restrict__ w3,
    const float* __restrict__ b3, const float* __restrict__ dinv,
    float4* __restrict__ h0, float4* __restrict__ zt) {
  __shared__ unsigned short arena[35840];
  __shared__ float lds_w3[384];
  unsigned short* lds_x = arena;
  unsigned short* lds_w = arena + 9216;
  unsigned short* lds_h = arena;
  unsigned short* lds_w2 = arena + 18432;

  const int tid = threadIdx.x;
  const int lane = tid & 63;
  const int wv = tid >> 6;
  const int fr = lane & 15;
  const int kq = (lane >> 4) * 8;
  const int rq = (lane >> 4) * 4;
  const int row0 = blockIdx.x * M_TILE;

  for (int i = tid; i < 384; i += 256) lds_w3[i] = w3[i];

#pragma unroll
  for (int it = 0; it < 8; ++it) {
    int idx = it * 256 + tid;
    int n = idx >> 4, c8 = idx & 15;
    uint4 v = *(const uint4*)(w2b + n * 128 + c8 * 8);
    *(uint4*)(lds_w2 + n * 136 + c8 * 8) = v;
  }

  f32x4 zero4 = {0.f, 0.f, 0.f, 0.f};
  f32x4 acc[2][8];
#pragma unroll
  for (int mt = 0; mt < 2; ++mt)
#pragma unroll
    for (int nt = 0; nt < 8; ++nt) acc[mt][nt] = zero4;

  for (int kb = 0; kb < D_IN; kb += BK) {
#pragma unroll
    for (int it = 0; it < 8; ++it) {
      int idx = it * 256 + tid;
      int r = idx >> 4, c4 = idx & 15;
      int gm = row0 + r;
      if (gm >= N_NODES) gm = N_NODES - 1;
      float4 v = *(const float4*)(x + (size_t)gm * D_IN + kb + c4 * 4);
      u16x4 o;
      o.x = f2bf(v.x); o.y = f2bf(v.y); o.z = f2bf(v.z); o.w = f2bf(v.w);
      *(u16x4*)(lds_x + r * 72 + c4 * 4) = o;
    }
#pragma unroll
    for (int it = 0; it < 4; ++it) {
      int idx = it * 256 + tid;
      int n = idx >> 3, c8 = idx & 7;
      uint4 v = *(const uint4*)(w1b + n * 512 + kb + c8 * 8);
      *(uint4*)(lds_w + n * 72 + c8 * 8) = v;
    }
    __syncthreads();
#pragma unroll
    for (int kk = 0; kk < BK; kk += 32) {
      bf16x8 a[2], b[8];
#pragma unroll
      for (int mt = 0; mt < 2; ++mt)
        a[mt] = __builtin_bit_cast(bf16x8, *(const u16x8*)(lds_x + (wv * 32 + mt * 16 + fr) * 72 + kk + kq));
#pragma unroll
      for (int nt = 0; nt < 8; ++nt)
        b[nt] = __builtin_bit_cast(bf16x8, *(const u16x8*)(lds_w + (nt * 16 + fr) * 72 + kk + kq));
#pragma unroll
      for (int mt = 0; mt < 2; ++mt)
#pragma unroll
        for (int nt = 0; nt < 8; ++nt)
          acc[mt][nt] = __builtin_amdgcn_mfma_f32_16x16x32_bf16(a[mt], b[nt], acc[mt][nt], 0, 0, 0);
    }
    __syncthreads();
  }

  float b1v[8], b2v[8];
#pragma unroll
  for (int nt = 0; nt < 8; ++nt) {
    b1v[nt] = bias1[nt * 16 + fr];
    b2v[nt] = bias2[nt * 16 + fr];
  }
  float hr[2][8][4];
#pragma unroll
  for (int mt = 0; mt < 2; ++mt)
#pragma unroll
    for (int nt = 0; nt < 8; ++nt)
#pragma unroll
      for (int r = 0; r < 4; ++r) {
        int rl = wv * 32 + mt * 16 + rq + r;
        int cl = nt * 16 + fr;
        float h = acc[mt][nt][r] + b1v[nt];
        h = h > 0.f ? h : 0.f;
        hr[mt][nt][r] = h;
        lds_h[rl * 136 + cl] = f2bf(h);
      }
  __syncthreads();

  f32x4 acc2[2][8];
#pragma unroll
  for (int mt = 0; mt < 2; ++mt)
#pragma unroll
    for (int nt = 0; nt < 8; ++nt) acc2[mt][nt] = zero4;
#pragma unroll
  for (int kk = 0; kk < 128; kk += 32) {
    bf16x8 a[2], b[8];
#pragma unroll
    for (int mt = 0; mt < 2; ++mt)
      a[mt] = __builtin_bit_cast(bf16x8, *(const u16x8*)(lds_h + (wv * 32 + mt * 16 + fr) * 136 + kk + kq));
#pragma unroll
    for (int nt = 0; nt < 8; ++nt)
      b[nt] = __builtin_bit_cast(bf16x8, *(const u16x8*)(lds_w2 + (nt * 16 + fr) * 136 + kk + kq));
#pragma unroll
    for (int mt = 0; mt < 2; ++mt)
#pragma unroll
      for (int nt = 0; nt < 8; ++nt)
        acc2[mt][nt] = __builtin_amdgcn_mfma_f32_16x16x32_bf16(a[mt], b[nt], acc2[mt][nt], 0, 0, 0);
  }
  __syncthreads();

#pragma unroll
  for (int mt = 0; mt < 2; ++mt)
#pragma unroll
    for (int nt = 0; nt < 8; ++nt)
#pragma unroll
      for (int r = 0; r < 4; ++r) {
        int rl = wv * 32 + mt * 16 + rq + r;
        int cl = nt * 16 + fr;
        float t2 = acc2[mt][nt][r] + b2v[nt];
        t2 = t2 > 0.f ? t2 : 0.f;
        lds_h[rl * 136 + cl] = f2bf(hr[mt][nt][r] + t2);
      }
  __syncthreads();

  if (tid < 128) {
    int m = tid;
    int gm = row0 + m;
    if (gm < N_NODES) {
      float a0 = 0.f, a1 = 0.f, a2 = 0.f;
#pragma unroll 8
      for (int c = 0; c < 128; ++c) {
        float hv = bf2f(lds_h[m * 136 + c]);
        a0 += hv * lds_w3[c];
        a1 += hv * lds_w3[128 + c];
        a2 += hv * lds_w3[256 + c];
      }
      float z0 = a0 + b3[0], z1 = a1 + b3[1], z2 = a2 + b3[2];
      float di = dinv[gm];
      h0[gm] = make_float4(z0, z1, z2, 0.f);
      zt[gm] = make_float4(di * z0, di * z1, di * z2, 0.f);
    }
  }
}

// ---------------- one APPNP iteration ----------------
__global__ void k_iter(const float4* __restrict__ ztin, float4* __restrict__ ztout,
                       const int* __restrict__ row_start, const unsigned* __restrict__ csr_col,
                       const float* __restrict__ dinv, const float4* __restrict__ h0) {
  int i = blockIdx.x * 256 + threadIdx.x;
  if (i >= N_NODES) return;
  float4 self = ztin[i];
  float sx = self.x, sy = self.y, sz = self.z;
  int r0 = row_start[i], r1 = row_start[i + 1];
  int j = r0;
  for (; j + 1 < r1; j += 2) {
    int c0 = csr_col[j], c1 = csr_col[j + 1];
    float4 v0 = ztin[c0];
    float4 v1 = ztin[c1];
    sx += v0.x + v1.x; sy += v0.y + v1.y; sz += v0.z + v1.z;
  }
  if (j < r1) {
    float4 v = ztin[csr_col[j]];
    sx += v.x; sy += v.y; sz += v.z;
  }
  float di = dinv[i];
  float4 h = h0[i];
  float zx = (1.f - ALPHA) * di * sx + ALPHA * h.x;
  float zy = (1.f - ALPHA) * di * sy + ALPHA * h.y;
  float zz = (1.f - ALPHA) * di * sz + ALPHA * h.z;
  ztout[i] = make_float4(di * zx, di * zy, di * zz, 0.f);
}

// ---------------- final iteration + log_softmax ----------------
__global__ void k_final(const float4* __restrict__ ztin,
                        const int* __restrict__ row_start, const unsigned* __restrict__ csr_col,
                        const float* __restrict__ dinv, const float4* __restrict__ h0,
                        float* __restrict__ out) {
  int i = blockIdx.x * 256 + threadIdx.x;
  if (i >= N_NODES) return;
  float4 self = ztin[i];
  float sx = self.x, sy = self.y, sz = self.z;
  int r0 = row_start[i], r1 = row_start[i + 1];
  int j = r0;
  for (; j + 1 < r1; j += 2) {
    int c0 = csr_col[j], c1 = csr_col[j + 1];
    float4 v0 = ztin[c0];
    float4 v1 = ztin[c1];
    sx += v0.x + v1.x; sy += v0.y + v1.y; sz += v0.z + v1.z;
  }
  if (j < r1) {
    float4 v = ztin[csr_col[j]];
    sx += v.x; sy += v.y; sz += v.z;
  }
  float di = dinv[i];
  float4 h = h0[i];
  float zx = (1.f - ALPHA) * di * sx + ALPHA * h.x;
  float zy = (1.f - ALPHA) * di * sy + ALPHA * h.y;
  float zz = (1.f - ALPHA) * di * sz + ALPHA * h.z;
  float mx = fmaxf(zx, fmaxf(zy, zz));
  float l = logf(expf(zx - mx) + expf(zy - mx) + expf(zz - mx));
  out[i * 3 + 0] = zx - mx - l;
  out[i * 3 + 1] = zy - mx - l;
  out[i * 3 + 2] = zz - mx - l;
}

extern "C" void kernel_launch(void* const* d_in, const int* in_sizes, int n_in,
                              void* d_out, int out_size, void* d_ws, size_t ws_size,
                              hipStream_t stream) {
  const float* x   = (const float*)d_in[0];
  const int*   ei  = (const int*)d_in[1];
  const float* w1  = (const float*)d_in[2];
  const float* b1  = (const float*)d_in[3];
  const float* g1  = (const float*)d_in[4];
  const float* be1 = (const float*)d_in[5];
  const float* m1  = (const float*)d_in[6];
  const float* v1  = (const float*)d_in[7];
  const float* w2  = (const float*)d_in[8];
  const float* b2  = (const float*)d_in[9];
  const float* g2  = (const float*)d_in[10];
  const float* be2 = (const float*)d_in[11];
  const float* m2  = (const float*)d_in[12];
  const float* v2  = (const float*)d_in[13];
  const float* w3  = (const float*)d_in[14];
  const float* b3  = (const float*)d_in[15];

  const int E = in_sizes[1] / 2;
  const int* srcA = ei;
  const int* dstA = ei + E;

  char* w = (char*)d_ws;
  size_t off = 0;
  auto alloc = [&](size_t bytes) -> void* {
    void* p = w + off;
    off = (off + bytes + 255) & ~(size_t)255;
    return p;
  };
  unsigned short* w1b   = (unsigned short*)alloc(65536 * 2);
  unsigned short* w2b   = (unsigned short*)alloc(16384 * 2);
  float* bias1          = (float*)alloc(128 * 4);
  float* bias2          = (float*)alloc(128 * 4);
  int*   deg            = (int*)alloc((size_t)N_NODES * 4);
  int*   row_start      = (int*)alloc(((size_t)N_NODES + 1) * 4);
  float* dinv           = (float*)alloc((size_t)N_NODES * 4);
  int*   bsum           = (int*)alloc(512 * 4);
  int*   bincur         = (int*)alloc((size_t)NCBIN * 4);
  float4* h0            = (float4*)alloc((size_t)N_NODES * 16);
  float4* ztA           = (float4*)alloc((size_t)N_NODES * 16);
  float4* ztB           = (float4*)alloc((size_t)N_NODES * 16);
  unsigned* csr_col     = (unsigned*)alloc((size_t)E * 4);
  unsigned* binned      = (unsigned*)alloc((size_t)NCBIN * BINCAP * 4);

  const int NB = (N_NODES + 255) / 256;        // 391
  const int NTILE = (E + TILE - 1) / TILE;     // 391 for E=3.2M

  k_prep<<<(82176 + NCBIN + 255) / 256, 256, 0, stream>>>(
      w1, b1, g1, be1, m1, v1, w2, b2, g2, be2, m2, v2, w1b, w2b, bias1, bias2, bincur);
  k_binA<<<NTILE, 256, 0, stream>>>(srcA, dstA, E, bincur, binned);
  k_binB1<<<NCBIN, 256, 0, stream>>>(binned, bincur, deg);
  k_scan1<<<NB, 256, 0, stream>>>(deg, bsum);
  k_scan2<<<1, 256, 0, stream>>>(bsum);
  k_scan3<<<NB, 256, 0, stream>>>(deg, bsum, row_start, dinv, E);
  k_binB2<<<NCBIN, 256, 0, stream>>>(binned, bincur, row_start, csr_col);
  k_mlp<<<(N_NODES + M_TILE - 1) / M_TILE, 256, 0, stream>>>(
      x, w1b, w2b, bias1, bias2, w3, b3, dinv, h0, ztA);

  const float4* zin = ztA;
  float4* zout = ztB;
  for (int k = 0; k < 9; ++k) {
    k_iter<<<NB, 256, 0, stream>>>(zin, zout, row_start, csr_col, dinv, h0);
    const float4* t = zout;
    zout = (float4*)zin;
    zin = t;
  }
  k_final<<<NB, 256, 0, stream>>>(zin, row_start, csr_col, dinv, h0, (float*)d_out);
}